// Round 11
// baseline (1395.096 us; speedup 1.0000x reference)
//
#include <hip/hip_runtime.h>
#include <hip/hip_bf16.h>

// CrossAttention (bug-faithful: per-position attention across the 16 heads).
// Round 11: GEMM LDS cut to 64KB (single-buffered A and B; halves staged at
// P1/P2/P3 right after their reads retire) -> 2 blocks/CU, cross-block
// latency hiding. Guards FIFO-derived: vmcnt(2)@P0, vmcnt(4)@P1, vmcnt(4)@P3.
// Rest = R10: cvt_in3, merged QKV 3D-grid, MFMA attn, permuted-Wo final GEMM.

typedef __attribute__((ext_vector_type(8))) __bf16 bf16x8;
typedef __attribute__((ext_vector_type(4))) float f32x4;

#define BM 128
#define BN 128
#define BK 64

__device__ __forceinline__ float bf2f(ushort u) {
  union { unsigned int i; float f; } c; c.i = ((unsigned int)u) << 16; return c.f;
}
__device__ __forceinline__ ushort f2b(float f) {
  union { float f; unsigned int i; } c; c.f = f;
  unsigned int x = c.i;
  return (ushort)((x + 0x7FFFu + ((x >> 16) & 1u)) >> 16);  // RNE
}

// ---------------- fp32 -> bf16 convert (single source) ---------------------
__global__ __launch_bounds__(256)
void cvt_f32_bf16(const float* __restrict__ s, ushort* __restrict__ d, int n8)
{
  int i = blockIdx.x * 256 + threadIdx.x;
  if (i >= n8) return;
  const float4* sp = reinterpret_cast<const float4*>(s) + (size_t)i * 2;
  float4 a = sp[0], b = sp[1];
  ushort u[8] = { f2b(a.x), f2b(a.y), f2b(a.z), f2b(a.w),
                  f2b(b.x), f2b(b.y), f2b(b.z), f2b(b.w) };
  reinterpret_cast<uint4*>(d)[i] = *reinterpret_cast<uint4*>(u);
}

// ------------- three converts in one launch (dst contiguous) ---------------
__global__ __launch_bounds__(256)
void cvt_in3(const float* __restrict__ a, const float* __restrict__ b,
             const float* __restrict__ c, ushort* __restrict__ dst, int n8each)
{
  int i = blockIdx.x * 256 + threadIdx.x;
  if (i >= 3 * n8each) return;
  const float* s; int j;
  if (i < n8each)          { s = a; j = i; }
  else if (i < 2 * n8each) { s = b; j = i - n8each; }
  else                     { s = c; j = i - 2 * n8each; }
  const float4* sp = reinterpret_cast<const float4*>(s) + (size_t)j * 2;
  float4 x = sp[0], y = sp[1];
  ushort u[8] = { f2b(x.x), f2b(x.y), f2b(x.z), f2b(x.w),
                  f2b(y.x), f2b(y.y), f2b(y.z), f2b(y.w) };
  reinterpret_cast<uint4*>(dst)[i] = *reinterpret_cast<uint4*>(u);
}

// --------- Wo convert with inverse k-permutation (matches Ot layout) -------
// Ot element idx holds O[i=4g+q][d=blk*16+c], idx = blk*256 + g*64 + c*4 + q.
__global__ __launch_bounds__(256)
void cvt_wo_perm(const float* __restrict__ w, ushort* __restrict__ o)
{
  int t = blockIdx.x * 256 + threadIdx.x;   // 0 .. 131071
  int n  = t >> 7;
  int i8 = (t & 127) << 3;
  int blk = i8 >> 8, g = (i8 >> 6) & 3, c = (i8 >> 2) & 15;
  const float* src = w + (size_t)n * 1024 + 4 * g * 64 + blk * 16 + c;
  ushort u[8];
  #pragma unroll
  for (int j = 0; j < 8; ++j)
    u[j] = f2b(src[(j & 3) * 64 + (j >> 2)]);
  *reinterpret_cast<uint4*>(o + (size_t)n * 1024 + i8) = *reinterpret_cast<uint4*>(u);
}

// ---------- 4-phase 256x256x64 bf16 GEMM body, 64KB single-buffered --------
// LDS: A [256][64] bf16 at 0 (32KB), B at 16384 ushorts (32KB). Halves of
// tile t+1 staged the phase after their region's reads retire:
// AloBlo@P1, Bhi@P2, Ahi@P3. Guards (FIFO): P0 vmcnt(2) retires Bhi(t);
// P1 vmcnt(4) retires Ahi(t); P3 vmcnt(4) retires AloBlo(t+1).
// Tail: P0 vmcnt(2), P1 vmcnt(0).
template<int CMODE>
__device__ __forceinline__
void gemm_body(const ushort* __restrict__ A, const ushort* __restrict__ Bw,
               const float* __restrict__ bias, void* __restrict__ Cv,
               int N, int K, ushort* lds)
{
  const int tid  = threadIdx.x;
  const int lane = tid & 63;
  const int wid  = tid >> 6;         // 0..7
  const int wm   = wid >> 2;         // 0..1
  const int wn   = wid & 3;          // 0..3

  const int nwg = gridDim.x * gridDim.y;
  int fid = blockIdx.y * gridDim.x + blockIdx.x;
  if ((nwg & 7) == 0) fid = (fid & 7) * (nwg >> 3) + (fid >> 3);
  const int bx = fid % gridDim.x;
  const int by = fid / gridDim.x;
  const int m0 = by * 256, n0 = bx * 256;

  const int NT = K >> 6;

  const int csw = ((lane & 7) ^ (lane >> 3)) << 3;   // pre-swizzled col offset
  // h: 0=A-lo, 1=A-hi, 2=B-lo, 3=B-hi (each 2 gload_lds)
  auto STAGE = [&](int h, int kt) {
    const ushort* base = (h >= 2) ? Bw : A;
    const int o0 = (h >= 2) ? n0 : m0;
    const int rl = (h & 1) * 128;
    #pragma unroll
    for (int j = 0; j < 2; ++j) {
      int rt = rl + j * 64 + wid * 8;
      const ushort* src = base + (size_t)(o0 + rt + (lane >> 3)) * K + kt * 64 + csw;
      ushort* dst = lds + (h >= 2 ? 16384 : 0) + rt * 64;
      __builtin_amdgcn_global_load_lds(
          (const __attribute__((address_space(1))) void*)src,
          (__attribute__((address_space(3))) void*)dst, 16, 0, 0);
    }
  };

  auto LDA = [&](int mi, int kk) -> bf16x8 {
    int row  = (mi & 3) * 16 + wm * 64 + (mi >> 2) * 128 + (lane & 15);
    int slot = kk * 4 + (lane >> 4);
    int byte = row * 128 + (((slot ^ (row & 7)) & 7) << 4);
    return *reinterpret_cast<const bf16x8*>((const char*)lds + byte);
  };
  auto LDB = [&](int ni, int kk) -> bf16x8 {
    int row  = (ni & 1) * 16 + wn * 32 + (ni >> 1) * 128 + (lane & 15);
    int slot = kk * 4 + (lane >> 4);
    int byte = row * 128 + (((slot ^ (row & 7)) & 7) << 4);
    return *reinterpret_cast<const bf16x8*>((const char*)(lds + 16384) + byte);
  };

  f32x4 acc[8][4] = {};
  bf16x8 af[4][2], bf[4][2];

  // prologue: stage tile 0 (FIFO: Alo, Blo, Bhi, Ahi); retire Alo+Blo.
  STAGE(0, 0); STAGE(2, 0); STAGE(3, 0); STAGE(1, 0);
  asm volatile("s_waitcnt vmcnt(4)" ::: "memory");
  __builtin_amdgcn_s_barrier();

  for (int t = 0; t < NT; ++t) {
    const bool pf = (t + 1) < NT;

    // ---- P0: reads Alo,Blo; guard retires Bhi(t) for P1 ----
    #pragma unroll
    for (int i = 0; i < 4; ++i) { af[i][0] = LDA(i, 0); af[i][1] = LDA(i, 1); }
    #pragma unroll
    for (int n = 0; n < 2; ++n) { bf[n][0] = LDB(n, 0); bf[n][1] = LDB(n, 1); }
    asm volatile("s_waitcnt vmcnt(2)" ::: "memory");
    __builtin_amdgcn_s_barrier();
    asm volatile("s_waitcnt lgkmcnt(0)" ::: "memory");
    __builtin_amdgcn_sched_barrier(0);
    __builtin_amdgcn_s_setprio(1);
    #pragma unroll
    for (int i = 0; i < 4; ++i)
      #pragma unroll
      for (int n = 0; n < 2; ++n)
        #pragma unroll
        for (int kk = 0; kk < 2; ++kk)
          acc[i][n] = __builtin_amdgcn_mfma_f32_16x16x32_bf16(af[i][kk], bf[n][kk], acc[i][n], 0, 0, 0);
    __builtin_amdgcn_s_setprio(0);
    __builtin_amdgcn_s_barrier();

    // ---- P1: stage Alo,Blo(t+1); reads Bhi; guard retires Ahi(t) ----
    if (pf) { STAGE(0, t + 1); STAGE(2, t + 1); }
    #pragma unroll
    for (int n = 0; n < 2; ++n) { bf[2 + n][0] = LDB(2 + n, 0); bf[2 + n][1] = LDB(2 + n, 1); }
    if (pf) asm volatile("s_waitcnt vmcnt(4)" ::: "memory");
    else    asm volatile("s_waitcnt vmcnt(0)" ::: "memory");
    __builtin_amdgcn_s_barrier();
    asm volatile("s_waitcnt lgkmcnt(0)" ::: "memory");
    __builtin_amdgcn_sched_barrier(0);
    __builtin_amdgcn_s_setprio(1);
    #pragma unroll
    for (int i = 0; i < 4; ++i)
      #pragma unroll
      for (int n = 0; n < 2; ++n)
        #pragma unroll
        for (int kk = 0; kk < 2; ++kk)
          acc[i][2 + n] = __builtin_amdgcn_mfma_f32_16x16x32_bf16(af[i][kk], bf[2 + n][kk], acc[i][2 + n], 0, 0, 0);
    __builtin_amdgcn_s_setprio(0);
    __builtin_amdgcn_s_barrier();

    // ---- P2: stage Bhi(t+1); reads Ahi; no guard (P3 has no reads) ----
    if (pf) STAGE(3, t + 1);
    #pragma unroll
    for (int i = 0; i < 4; ++i) { af[i][0] = LDA(4 + i, 0); af[i][1] = LDA(4 + i, 1); }
    __builtin_amdgcn_s_barrier();
    asm volatile("s_waitcnt lgkmcnt(0)" ::: "memory");
    __builtin_amdgcn_sched_barrier(0);
    __builtin_amdgcn_s_setprio(1);
    #pragma unroll
    for (int i = 0; i < 4; ++i)
      #pragma unroll
      for (int n = 0; n < 2; ++n)
        #pragma unroll
        for (int kk = 0; kk < 2; ++kk)
          acc[4 + i][n] = __builtin_amdgcn_mfma_f32_16x16x32_bf16(af[i][kk], bf[n][kk], acc[4 + i][n], 0, 0, 0);
    __builtin_amdgcn_s_setprio(0);
    __builtin_amdgcn_s_barrier();

    // ---- P3: stage Ahi(t+1); guard retires AloBlo(t+1) for next P0 ----
    if (pf) { STAGE(1, t + 1);
              asm volatile("s_waitcnt vmcnt(4)" ::: "memory"); }
    __builtin_amdgcn_s_barrier();
    __builtin_amdgcn_s_setprio(1);
    #pragma unroll
    for (int i = 0; i < 4; ++i)
      #pragma unroll
      for (int n = 0; n < 2; ++n)
        #pragma unroll
        for (int kk = 0; kk < 2; ++kk)
          acc[4 + i][2 + n] = __builtin_amdgcn_mfma_f32_16x16x32_bf16(af[i][kk], bf[2 + n][kk], acc[4 + i][2 + n], 0, 0, 0);
    __builtin_amdgcn_s_setprio(0);
    __builtin_amdgcn_s_barrier();
  }

  // epilogue: +bias, C-write (C/D layout: col=lane&15, row=(lane>>4)*4+q)
  #pragma unroll
  for (int ni = 0; ni < 4; ++ni) {
    int col = n0 + (ni & 1) * 16 + wn * 32 + (ni >> 1) * 128 + (lane & 15);
    float bv = bias[col];
    #pragma unroll
    for (int mi = 0; mi < 8; ++mi) {
      int row0 = m0 + (mi & 3) * 16 + wm * 64 + (mi >> 2) * 128 + ((lane >> 4) << 2);
      #pragma unroll
      for (int q = 0; q < 4; ++q) {
        float v = acc[mi][ni][q] + bv;
        if constexpr (CMODE == 0)
          ((float*)Cv)[(size_t)(row0 + q) * N + col] = v;
        else
          ((ushort*)Cv)[(size_t)(row0 + q) * N + col] = f2b(v);
      }
    }
  }
}

// single-GEMM wrapper
template<int CMODE>
__global__ __launch_bounds__(512, 4)
void gemm8p(const ushort* __restrict__ A, const ushort* __restrict__ Bw,
            const float* __restrict__ bias, void* __restrict__ Cv,
            int M, int N, int K)
{
  extern __shared__ ushort lds[];
  gemm_body<CMODE>(A, Bw, bias, Cv, N, K, lds);
}

// merged QKV projection wrapper: z = 0/1/2 selects input, weight, bias, out
__global__ __launch_bounds__(512, 4)
void gemm8p_qkv(const ushort* __restrict__ Abase, const ushort* __restrict__ Wbase,
                const float* __restrict__ b0, const float* __restrict__ b1,
                const float* __restrict__ b2, ushort* __restrict__ Cbase,
                int M, int N, int K)
{
  extern __shared__ ushort lds[];
  const int z = blockIdx.z;
  const size_t slot = (size_t)M * K;
  const size_t wsl  = (size_t)N * K;
  const float* bias = (z == 0) ? b0 : (z == 1) ? b1 : b2;
  gemm_body<1>(Abase + z * slot, Wbase + z * wsl, bias,
               (void*)(Cbase + z * (size_t)M * N), N, K, lds);
}

// ---------------- MFMA attention, NATURAL V (per position) -----------------
__global__ __launch_bounds__(256)
void attn_mfma2(const ushort* __restrict__ Q, const ushort* __restrict__ Kh,
                const ushort* __restrict__ V, ushort* __restrict__ Ot, int P)
{
  const int lane = threadIdx.x & 63;
  const int wid  = threadIdx.x >> 6;
  const int g = lane >> 4, c = lane & 15;
  const int stride = gridDim.x * 4;

  for (int p = blockIdx.x * 4 + wid; p < P; p += stride) {
    const ushort* qb = Q  + (size_t)p * 1024;
    const ushort* kb = Kh + (size_t)p * 1024;
    const ushort* vb = V  + (size_t)p * 1024;

    bf16x8 qf0 = *reinterpret_cast<const bf16x8*>(qb + c * 64 + g * 8);
    bf16x8 qf1 = *reinterpret_cast<const bf16x8*>(qb + c * 64 + 32 + g * 8);
    bf16x8 kf0 = *reinterpret_cast<const bf16x8*>(kb + c * 64 + g * 8);
    bf16x8 kf1 = *reinterpret_cast<const bf16x8*>(kb + c * 64 + 32 + g * 8);

    f32x4 s = {};
    s = __builtin_amdgcn_mfma_f32_16x16x32_bf16(kf0, qf0, s, 0, 0, 0);
    s = __builtin_amdgcn_mfma_f32_16x16x32_bf16(kf1, qf1, s, 0, 0, 0);

    float s0 = s[0] * 0.125f, s1 = s[1] * 0.125f;
    float s2 = s[2] * 0.125f, s3 = s[3] * 0.125f;
    float m = fmaxf(fmaxf(s0, s1), fmaxf(s2, s3));
    m = fmaxf(m, __shfl_xor(m, 16));
    m = fmaxf(m, __shfl_xor(m, 32));
    float e0 = __expf(s0 - m), e1 = __expf(s1 - m);
    float e2 = __expf(s2 - m), e3 = __expf(s3 - m);
    float sum = e0 + e1 + e2 + e3;
    sum += __shfl_xor(sum, 16);
    sum += __shfl_xor(sum, 32);
    float r = 1.0f / sum;

    uint pk0 = (uint)f2b(e0 * r) | ((uint)f2b(e1 * r) << 16);  // P[c][4g+0,1]
    uint pk1 = (uint)f2b(e2 * r) | ((uint)f2b(e3 * r) << 16);  // P[c][4g+2,3]

    int srcA = (((2 * g) & 3) << 4) | c;
    int srcB = (((2 * g + 1) & 3) << 4) | c;
    uint a0 = (uint)__shfl((int)pk0, srcA);
    uint a1 = (uint)__shfl((int)pk1, srcA);
    uint a2 = (uint)__shfl((int)pk0, srcB);
    uint a3 = (uint)__shfl((int)pk1, srcB);
    if (g >= 2) { a0 = 0; a1 = 0; a2 = 0; a3 = 0; }
    union { uint u[4]; bf16x8 v; } pa;
    pa.u[0] = a0; pa.u[1] = a1; pa.u[2] = a2; pa.u[3] = a3;

    ushort* ob = Ot + (size_t)p * 1024;
    #pragma unroll
    for (int blk = 0; blk < 4; ++blk) {
      union { ushort u[8]; bf16x8 v; } vf;
      #pragma unroll
      for (int e = 0; e < 8; ++e)
        vf.u[e] = vb[(8 * (g & 1) + e) * 64 + blk * 16 + c];
      f32x4 o = {};
      o = __builtin_amdgcn_mfma_f32_16x16x32_bf16(pa.v, vf.v, o, 0, 0, 0);
      uint lo = (uint)f2b(o[0]) | ((uint)f2b(o[1]) << 16);
      uint hi = (uint)f2b(o[2]) | ((uint)f2b(o[3]) << 16);
      uint2 w2; w2.x = lo; w2.y = hi;
      *reinterpret_cast<uint2*>(ob + blk * 256 + g * 64 + c * 4) = w2;
    }
  }
}

// --------- fallback GEMM (round-1, fp32 reg-staged, XOR-swizzled LDS) ------
template<bool A_IS_BF16, bool OUT_BF16>
__global__ __launch_bounds__(256)
void gemm_bt(const void* __restrict__ Av, const float* __restrict__ B,
             const float* __restrict__ bias, void* __restrict__ Cv,
             int M, int N, int K)
{
  __shared__ ushort As[BM * BK];
  __shared__ ushort Bs[BN * BK];

  const int tid  = threadIdx.x;
  const int lane = tid & 63;
  const int wid  = tid >> 6;
  const int wr   = wid >> 1;
  const int wc   = wid & 1;
  const int m0   = blockIdx.y * BM;
  const int n0   = blockIdx.x * BN;

  f32x4 acc[4][4] = {};

  const int r   = tid >> 1;
  const int seg = (tid & 1) * 32;

  for (int k0 = 0; k0 < K; k0 += BK) {
    {
      ushort tmp[32];
      if constexpr (A_IS_BF16) {
        const ushort* gA = (const ushort*)Av + (size_t)(m0 + r) * K + k0 + seg;
        #pragma unroll
        for (int u = 0; u < 4; ++u)
          *reinterpret_cast<uint4*>(&tmp[u * 8]) =
              *reinterpret_cast<const uint4*>(gA + u * 8);
      } else {
        const float* gA = (const float*)Av + (size_t)(m0 + r) * K + k0 + seg;
        #pragma unroll
        for (int u = 0; u < 8; ++u) {
          float4 f = *reinterpret_cast<const float4*>(gA + u * 4);
          tmp[u * 4 + 0] = f2b(f.x); tmp[u * 4 + 1] = f2b(f.y);
          tmp[u * 4 + 2] = f2b(f.z); tmp[u * 4 + 3] = f2b(f.w);
        }
      }
      #pragma unroll
      for (int s4 = 0; s4 < 4; ++s4) {
        int slot = (seg >> 3) + s4;
        int byte = r * 128 + ((slot ^ (r & 7)) << 4);
        *reinterpret_cast<uint4*>((char*)As + byte) =
            *reinterpret_cast<uint4*>(&tmp[s4 * 8]);
      }
    }
    {
      const float* gB = B + (size_t)(n0 + r) * K + k0 + seg;
      ushort tmp[32];
      #pragma unroll
      for (int u = 0; u < 8; ++u) {
        float4 f = *reinterpret_cast<const float4*>(gB + u * 4);
        tmp[u * 4 + 0] = f2b(f.x); tmp[u * 4 + 1] = f2b(f.y);
        tmp[u * 4 + 2] = f2b(f.z); tmp[u * 4 + 3] = f2b(f.w);
      }
      #pragma unroll
      for (int s4 = 0; s4 < 4; ++s4) {
        int slot = (seg >> 3) + s4;
        int byte = r * 128 + ((slot ^ (r & 7)) << 4);
        *reinterpret_cast<uint4*>((char*)Bs + byte) =
            *reinterpret_cast<uint4*>(&tmp[s4 * 8]);
      }
    }
    __syncthreads();

    #pragma unroll
    for (int kk = 0; kk < 2; ++kk) {
      const int kbase = kk * 32 + ((lane >> 4) << 3);
      const int slot  = kbase >> 3;
      bf16x8 af[4], bfr[4];
      #pragma unroll
      for (int mi = 0; mi < 4; ++mi) {
        int row = wr * 64 + mi * 16 + (lane & 15);
        af[mi] = *reinterpret_cast<const bf16x8*>(
            (const char*)As + row * 128 + ((slot ^ (row & 7)) << 4));
      }
      #pragma unroll
      for (int ni = 0; ni < 4; ++ni) {
        int row = wc * 64 + ni * 16 + (lane & 15);
        bfr[ni] = *reinterpret_cast<const bf16x8*>(
            (const char*)Bs + row * 128 + ((slot ^ (row & 7)) << 4));
      }
      #pragma unroll
      for (int mi = 0; mi < 4; ++mi)
        #pragma unroll
        for (int ni = 0; ni < 4; ++ni)
          acc[mi][ni] = __builtin_amdgcn_mfma_f32_16x16x32_bf16(
              af[mi], bfr[ni], acc[mi][ni], 0, 0, 0);
    }
    __syncthreads();
  }

  #pragma unroll
  for (int ni = 0; ni < 4; ++ni) {
    int col = n0 + wc * 64 + ni * 16 + (lane & 15);
    float bv = bias[col];
    #pragma unroll
    for (int mi = 0; mi < 4; ++mi) {
      int row0 = m0 + wr * 64 + mi * 16 + ((lane >> 4) << 2);
      #pragma unroll
      for (int q = 0; q < 4; ++q) {
        float v = acc[mi][ni][q] + bv;
        if constexpr (OUT_BF16)
          ((ushort*)Cv)[(size_t)(row0 + q) * N + col] = f2b(v);
        else
          ((float*)Cv)[(size_t)(row0 + q) * N + col] = v;
      }
    }
  }
}

// ------------- fallback attention (round-1, LDS scalar) --------------------
__global__ __launch_bounds__(256)
void attn_kernel(const ushort* __restrict__ Q, const ushort* __restrict__ Kh,
                 const ushort* __restrict__ V, ushort* __restrict__ O)
{
  __shared__ float smem[4][3][16][68];
  const int tid  = threadIdx.x;
  const int wid  = tid >> 6;
  const int lane = tid & 63;
  const size_t p = (size_t)blockIdx.x * 4 + wid;

  {
    const ushort* srcs[3] = { Q + p * 1024, Kh + p * 1024, V + p * 1024 };
    const int i  = lane >> 2;
    const int d0 = (lane & 3) * 16;
    #pragma unroll
    for (int m = 0; m < 3; ++m) {
      const ushort* s = srcs[m] + lane * 16;
      ushort u[16];
      *reinterpret_cast<uint4*>(&u[0]) = *reinterpret_cast<const uint4*>(s);
      *reinterpret_cast<uint4*>(&u[8]) = *reinterpret_cast<const uint4*>(s + 8);
      #pragma unroll
      for (int e = 0; e < 16; ++e) smem[wid][m][i][d0 + e] = bf2f(u[e]);
    }
  }
  __syncthreads();

  const int i  = lane >> 2;
  const int jg = lane & 3;
  const float* qrow = smem[wid][0][i];
  const float* k0r = smem[wid][1][jg * 4 + 0];
  const float* k1r = smem[wid][1][jg * 4 + 1];
  const float* k2r = smem[wid][1][jg * 4 + 2];
  const float* k3r = smem[wid][1][jg * 4 + 3];

  float s0 = 0.f, s1 = 0.f, s2 = 0.f, s3 = 0.f;
  #pragma unroll
  for (int d = 0; d < 64; ++d) {
    float qv = qrow[d];
    s0 += qv * k0r[d]; s1 += qv * k1r[d];
    s2 += qv * k2r[d]; s3 += qv * k3r[d];
  }
  const float scale = 0.125f;
  s0 *= scale; s1 *= scale; s2 *= scale; s3 *= scale;

  float mx = fmaxf(fmaxf(s0, s1), fmaxf(s2, s3));
  mx = fmaxf(mx, __shfl_xor(mx, 1));
  mx = fmaxf(mx, __shfl_xor(mx, 2));
  float e0 = __expf(s0 - mx), e1 = __expf(s1 - mx);
  float e2 = __expf(s2 - mx), e3 = __expf(s3 - mx);
  float sum = e0 + e1 + e2 + e3;
  sum += __shfl_xor(sum, 1);
  sum += __shfl_xor(sum, 2);
  float inv = 1.0f / sum;
  e0 *= inv; e1 *= inv; e2 *= inv; e3 *= inv;

  const float* v0r = smem[wid][2][jg * 4 + 0];
  const float* v1r = smem[wid][2][jg * 4 + 1];
  const float* v2r = smem[wid][2][jg * 4 + 2];
  const float* v3r = smem[wid][2][jg * 4 + 3];
  ushort* orow = O + p * 1024 + i * 64;

  #pragma unroll
  for (int cc = 0; cc < 4; ++cc) {
    float po[16];
    #pragma unroll
    for (int dd = 0; dd < 16; ++dd) {
      int d = cc * 16 + dd;
      po[dd] = e0 * v0r[d] + e1 * v1r[d] + e2 * v2r[d] + e3 * v3r[d];
    }
    #pragma unroll
    for (int dd = 0; dd < 16; ++dd) {
      po[dd] += __shfl_xor(po[dd], 1);
      po[dd] += __shfl_xor(po[dd], 2);
    }
    if (jg == cc) {
      #pragma unroll
      for (int dd = 0; dd < 16; ++dd) orow[cc * 16 + dd] = f2b(po[dd]);
    }
  }
}

extern "C" void kernel_launch(void* const* d_in, const int* in_sizes, int n_in,
                              void* d_out, int out_size, void* d_ws, size_t ws_size,
                              hipStream_t stream)
{
  const float* query = (const float*)d_in[0];
  const float* key_  = (const float*)d_in[1];
  const float* value = (const float*)d_in[2];
  const float* wq_w  = (const float*)d_in[3];
  const float* wq_b  = (const float*)d_in[4];
  const float* wk_w  = (const float*)d_in[5];
  const float* wk_b  = (const float*)d_in[6];
  const float* wv_w  = (const float*)d_in[7];
  const float* wv_b  = (const float*)d_in[8];
  const float* fo_w  = (const float*)d_in[9];
  const float* fo_b  = (const float*)d_in[10];

  const int K = 1024, N = 1024;
  const int M = in_sizes[0] / K;       // 16384
  const size_t slot = (size_t)M * N;
  const size_t wsl  = (size_t)N * K;
  const size_t need_big = (6 * slot + 4 * wsl) * sizeof(ushort);  // 200 MiB
  const size_t need_mid = (4 * slot + 4 * wsl) * sizeof(ushort);  // 136 MiB
  const bool dims_ok = (M % 256) == 0 && N == 1024 && K == 1024;

  const int n8w = (int)(wsl / 8);       // 131072
  const int n8s = (int)(slot / 8);

  if (ws_size >= need_big && dims_ok) {
    hipFuncSetAttribute(reinterpret_cast<const void*>(gemm8p<0>),
                        hipFuncAttributeMaxDynamicSharedMemorySize, 65536);
    hipFuncSetAttribute(reinterpret_cast<const void*>(gemm8p_qkv),
                        hipFuncAttributeMaxDynamicSharedMemorySize, 65536);

    ushort* I0 = (ushort*)d_ws;           // q,k,v bf16 inputs (contiguous)
    ushort* P1 = I0 + 3 * slot;           // Q,K,V projections (contiguous)
    ushort* Wq = P1 + 3 * slot;           // Wq,Wk,Wv contiguous
    ushort* Wo = Wq + 3 * wsl;            // permuted-k Wo
    ushort* Ot = I0;                      // attn out reuses input slot 0

    dim3 g8(N / 256, M / 256);            // (4, 64)
    dim3 g8z(N / 256, M / 256, 3);        // merged QKV
    dim3 b8(512);

    cvt_in3<<<dim3((3 * n8s + 255) / 256), dim3(256), 0, stream>>>(
        query, key_, value, I0, n8s);
    cvt_in3<<<dim3((3 * n8w + 255) / 256), dim3(256), 0, stream>>>(
        wq_w, wk_w, wv_w, Wq, n8w);
    cvt_wo_perm<<<dim3(512), dim3(256), 0, stream>>>(fo_w, Wo);

    gemm8p_qkv<<<g8z, b8, 65536, stream>>>(I0, Wq, wq_b, wk_b, wv_b, P1, M, N, K);

    attn_mfma2<<<dim3(2048), dim3(256), 0, stream>>>(
        P1, P1 + slot, P1 + 2 * slot, Ot, M);
    gemm8p<0><<<g8, b8, 65536, stream>>>(Ot, Wo, fo_b, d_out, M, N, K);
  } else if (ws_size >= need_mid && dims_ok) {
    hipFuncSetAttribute(reinterpret_cast<const void*>(gemm8p<0>),
                        hipFuncAttributeMaxDynamicSharedMemorySize, 65536);
    hipFuncSetAttribute(reinterpret_cast<const void*>(gemm8p<1>),
                        hipFuncAttributeMaxDynamicSharedMemorySize, 65536);

    ushort* S0 = (ushort*)d_ws;
    ushort* S1 = S0 + slot;
    ushort* S2 = S1 + slot;
    ushort* S3 = S2 + slot;
    ushort* Wq = S3 + slot;
    ushort* Wo = Wq + 3 * wsl;

    dim3 g8(N / 256, M / 256);
    dim3 b8(512);

    cvt_in3<<<dim3((3 * n8w + 255) / 256), dim3(256), 0, stream>>>(
        wq_w, wk_w, wv_w, Wq, n8w);
    cvt_wo_perm<<<dim3(512), dim3(256), 0, stream>>>(fo_w, Wo);

    cvt_f32_bf16<<<dim3((n8s + 255) / 256), dim3(256), 0, stream>>>(query, S0, n8s);
    gemm8p<1><<<g8, b8, 65536, stream>>>(S0, Wq,           wq_b, S1, M, N, K);
    cvt_f32_bf16<<<dim3((n8s + 255) / 256), dim3(256), 0, stream>>>(key_, S0, n8s);
    gemm8p<1><<<g8, b8, 65536, stream>>>(S0, Wq + wsl,     wk_b, S2, M, N, K);
    cvt_f32_bf16<<<dim3((n8s + 255) / 256), dim3(256), 0, stream>>>(value, S0, n8s);
    gemm8p<1><<<g8, b8, 65536, stream>>>(S0, Wq + 2 * wsl, wv_b, S3, M, N, K);

    attn_mfma2<<<dim3(2048), dim3(256), 0, stream>>>(S1, S2, S3, S0, M);
    gemm8p<0><<<g8, b8, 65536, stream>>>(S0, Wo, fo_b, d_out, M, N, K);
  } else {
    dim3 grid(N / BN, M / BM);
    ushort* Qb = (ushort*)d_ws;
    ushort* Kb = Qb + slot;
    ushort* Vb = Kb + slot;
    ushort* Ob = Vb + slot;
    gemm_bt<false, true><<<grid, dim3(256), 0, stream>>>(query, wq_w, wq_b, Qb, M, N, K);
    gemm_bt<false, true><<<grid, dim3(256), 0, stream>>>(key_,  wk_w, wk_b, Kb, M, N, K);
    gemm_bt<false, true><<<grid, dim3(256), 0, stream>>>(value, wv_w, wv_b, Vb, M, N, K);
    attn_kernel<<<dim3(M / 4), dim3(256), 0, stream>>>(Qb, Kb, Vb, Ob);
    gemm_bt<true, false><<<grid, dim3(256), 0, stream>>>(Ob, fo_w, fo_b, d_out, M, N, K);
  }
}

// Round 12
// 230.295 us; speedup vs baseline: 6.0579x; 6.0579x over previous
//
#include <hip/hip_runtime.h>
#include <hip/hip_bf16.h>

// CrossAttention (bug-faithful: per-position attention across the 16 heads).
// Round 12: R11 schedule (64KB single-buffered GEMM LDS, staged-after-retire,
// FIFO guards) with launch_bounds fixed: (512,2) not (512,4). R11's failure
// was regalloc strangulation (VGPR 64, massive spill, 4GB scratch traffic),
// NOT the schedule. 2 blocks/CU now comes from LDS fit (64KB*2 <= 160KB)
// with full 112-VGPR allocation.

typedef __attribute__((ext_vector_type(8))) __bf16 bf16x8;
typedef __attribute__((ext_vector_type(4))) float f32x4;

#define BM 128
#define BN 128
#define BK 64

__device__ __forceinline__ float bf2f(ushort u) {
  union { unsigned int i; float f; } c; c.i = ((unsigned int)u) << 16; return c.f;
}
__device__ __forceinline__ ushort f2b(float f) {
  union { float f; unsigned int i; } c; c.f = f;
  unsigned int x = c.i;
  return (ushort)((x + 0x7FFFu + ((x >> 16) & 1u)) >> 16);  // RNE
}

// ---------------- fp32 -> bf16 convert (single source) ---------------------
__global__ __launch_bounds__(256)
void cvt_f32_bf16(const float* __restrict__ s, ushort* __restrict__ d, int n8)
{
  int i = blockIdx.x * 256 + threadIdx.x;
  if (i >= n8) return;
  const float4* sp = reinterpret_cast<const float4*>(s) + (size_t)i * 2;
  float4 a = sp[0], b = sp[1];
  ushort u[8] = { f2b(a.x), f2b(a.y), f2b(a.z), f2b(a.w),
                  f2b(b.x), f2b(b.y), f2b(b.z), f2b(b.w) };
  reinterpret_cast<uint4*>(d)[i] = *reinterpret_cast<uint4*>(u);
}

// ------------- three converts in one launch (dst contiguous) ---------------
__global__ __launch_bounds__(256)
void cvt_in3(const float* __restrict__ a, const float* __restrict__ b,
             const float* __restrict__ c, ushort* __restrict__ dst, int n8each)
{
  int i = blockIdx.x * 256 + threadIdx.x;
  if (i >= 3 * n8each) return;
  const float* s; int j;
  if (i < n8each)          { s = a; j = i; }
  else if (i < 2 * n8each) { s = b; j = i - n8each; }
  else                     { s = c; j = i - 2 * n8each; }
  const float4* sp = reinterpret_cast<const float4*>(s) + (size_t)j * 2;
  float4 x = sp[0], y = sp[1];
  ushort u[8] = { f2b(x.x), f2b(x.y), f2b(x.z), f2b(x.w),
                  f2b(y.x), f2b(y.y), f2b(y.z), f2b(y.w) };
  reinterpret_cast<uint4*>(dst)[i] = *reinterpret_cast<uint4*>(u);
}

// --------- Wo convert with inverse k-permutation (matches Ot layout) -------
// Ot element idx holds O[i=4g+q][d=blk*16+c], idx = blk*256 + g*64 + c*4 + q.
__global__ __launch_bounds__(256)
void cvt_wo_perm(const float* __restrict__ w, ushort* __restrict__ o)
{
  int t = blockIdx.x * 256 + threadIdx.x;   // 0 .. 131071
  int n  = t >> 7;
  int i8 = (t & 127) << 3;
  int blk = i8 >> 8, g = (i8 >> 6) & 3, c = (i8 >> 2) & 15;
  const float* src = w + (size_t)n * 1024 + 4 * g * 64 + blk * 16 + c;
  ushort u[8];
  #pragma unroll
  for (int j = 0; j < 8; ++j)
    u[j] = f2b(src[(j & 3) * 64 + (j >> 2)]);
  *reinterpret_cast<uint4*>(o + (size_t)n * 1024 + i8) = *reinterpret_cast<uint4*>(u);
}

// ---------- 4-phase 256x256x64 bf16 GEMM body, 64KB single-buffered --------
// LDS: A [256][64] bf16 at 0 (32KB), B at 16384 ushorts (32KB). Halves of
// tile t+1 staged the phase after their region's reads retire:
// AloBlo@P1, Bhi@P2, Ahi@P3. Guards (FIFO): P0 vmcnt(2) retires Bhi(t);
// P1 vmcnt(4) retires Ahi(t); P3 vmcnt(4) retires AloBlo(t+1).
// Tail: P0 vmcnt(2), P1 vmcnt(0).
template<int CMODE>
__device__ __forceinline__
void gemm_body(const ushort* __restrict__ A, const ushort* __restrict__ Bw,
               const float* __restrict__ bias, void* __restrict__ Cv,
               int N, int K, ushort* lds)
{
  const int tid  = threadIdx.x;
  const int lane = tid & 63;
  const int wid  = tid >> 6;         // 0..7
  const int wm   = wid >> 2;         // 0..1
  const int wn   = wid & 3;          // 0..3

  const int nwg = gridDim.x * gridDim.y;
  int fid = blockIdx.y * gridDim.x + blockIdx.x;
  if ((nwg & 7) == 0) fid = (fid & 7) * (nwg >> 3) + (fid >> 3);
  const int bx = fid % gridDim.x;
  const int by = fid / gridDim.x;
  const int m0 = by * 256, n0 = bx * 256;

  const int NT = K >> 6;

  const int csw = ((lane & 7) ^ (lane >> 3)) << 3;   // pre-swizzled col offset
  // h: 0=A-lo, 1=A-hi, 2=B-lo, 3=B-hi (each 2 gload_lds)
  auto STAGE = [&](int h, int kt) {
    const ushort* base = (h >= 2) ? Bw : A;
    const int o0 = (h >= 2) ? n0 : m0;
    const int rl = (h & 1) * 128;
    #pragma unroll
    for (int j = 0; j < 2; ++j) {
      int rt = rl + j * 64 + wid * 8;
      const ushort* src = base + (size_t)(o0 + rt + (lane >> 3)) * K + kt * 64 + csw;
      ushort* dst = lds + (h >= 2 ? 16384 : 0) + rt * 64;
      __builtin_amdgcn_global_load_lds(
          (const __attribute__((address_space(1))) void*)src,
          (__attribute__((address_space(3))) void*)dst, 16, 0, 0);
    }
  };

  auto LDA = [&](int mi, int kk) -> bf16x8 {
    int row  = (mi & 3) * 16 + wm * 64 + (mi >> 2) * 128 + (lane & 15);
    int slot = kk * 4 + (lane >> 4);
    int byte = row * 128 + (((slot ^ (row & 7)) & 7) << 4);
    return *reinterpret_cast<const bf16x8*>((const char*)lds + byte);
  };
  auto LDB = [&](int ni, int kk) -> bf16x8 {
    int row  = (ni & 1) * 16 + wn * 32 + (ni >> 1) * 128 + (lane & 15);
    int slot = kk * 4 + (lane >> 4);
    int byte = row * 128 + (((slot ^ (row & 7)) & 7) << 4);
    return *reinterpret_cast<const bf16x8*>((const char*)(lds + 16384) + byte);
  };

  f32x4 acc[8][4] = {};
  bf16x8 af[4][2], bf[4][2];

  // prologue: stage tile 0 (FIFO: Alo, Blo, Bhi, Ahi); retire Alo+Blo.
  STAGE(0, 0); STAGE(2, 0); STAGE(3, 0); STAGE(1, 0);
  asm volatile("s_waitcnt vmcnt(4)" ::: "memory");
  __builtin_amdgcn_s_barrier();

  for (int t = 0; t < NT; ++t) {
    const bool pf = (t + 1) < NT;

    // ---- P0: reads Alo,Blo; guard retires Bhi(t) for P1 ----
    #pragma unroll
    for (int i = 0; i < 4; ++i) { af[i][0] = LDA(i, 0); af[i][1] = LDA(i, 1); }
    #pragma unroll
    for (int n = 0; n < 2; ++n) { bf[n][0] = LDB(n, 0); bf[n][1] = LDB(n, 1); }
    asm volatile("s_waitcnt vmcnt(2)" ::: "memory");
    __builtin_amdgcn_s_barrier();
    asm volatile("s_waitcnt lgkmcnt(0)" ::: "memory");
    __builtin_amdgcn_sched_barrier(0);
    __builtin_amdgcn_s_setprio(1);
    #pragma unroll
    for (int i = 0; i < 4; ++i)
      #pragma unroll
      for (int n = 0; n < 2; ++n)
        #pragma unroll
        for (int kk = 0; kk < 2; ++kk)
          acc[i][n] = __builtin_amdgcn_mfma_f32_16x16x32_bf16(af[i][kk], bf[n][kk], acc[i][n], 0, 0, 0);
    __builtin_amdgcn_s_setprio(0);
    __builtin_amdgcn_s_barrier();

    // ---- P1: stage Alo,Blo(t+1); reads Bhi; guard retires Ahi(t) ----
    if (pf) { STAGE(0, t + 1); STAGE(2, t + 1); }
    #pragma unroll
    for (int n = 0; n < 2; ++n) { bf[2 + n][0] = LDB(2 + n, 0); bf[2 + n][1] = LDB(2 + n, 1); }
    if (pf) asm volatile("s_waitcnt vmcnt(4)" ::: "memory");
    else    asm volatile("s_waitcnt vmcnt(0)" ::: "memory");
    __builtin_amdgcn_s_barrier();
    asm volatile("s_waitcnt lgkmcnt(0)" ::: "memory");
    __builtin_amdgcn_sched_barrier(0);
    __builtin_amdgcn_s_setprio(1);
    #pragma unroll
    for (int i = 0; i < 4; ++i)
      #pragma unroll
      for (int n = 0; n < 2; ++n)
        #pragma unroll
        for (int kk = 0; kk < 2; ++kk)
          acc[i][2 + n] = __builtin_amdgcn_mfma_f32_16x16x32_bf16(af[i][kk], bf[2 + n][kk], acc[i][2 + n], 0, 0, 0);
    __builtin_amdgcn_s_setprio(0);
    __builtin_amdgcn_s_barrier();

    // ---- P2: stage Bhi(t+1); reads Ahi; no guard (P3 has no reads) ----
    if (pf) STAGE(3, t + 1);
    #pragma unroll
    for (int i = 0; i < 4; ++i) { af[i][0] = LDA(4 + i, 0); af[i][1] = LDA(4 + i, 1); }
    __builtin_amdgcn_s_barrier();
    asm volatile("s_waitcnt lgkmcnt(0)" ::: "memory");
    __builtin_amdgcn_sched_barrier(0);
    __builtin_amdgcn_s_setprio(1);
    #pragma unroll
    for (int i = 0; i < 4; ++i)
      #pragma unroll
      for (int n = 0; n < 2; ++n)
        #pragma unroll
        for (int kk = 0; kk < 2; ++kk)
          acc[4 + i][n] = __builtin_amdgcn_mfma_f32_16x16x32_bf16(af[i][kk], bf[n][kk], acc[4 + i][n], 0, 0, 0);
    __builtin_amdgcn_s_setprio(0);
    __builtin_amdgcn_s_barrier();

    // ---- P3: stage Ahi(t+1); guard retires AloBlo(t+1) for next P0 ----
    if (pf) { STAGE(1, t + 1);
              asm volatile("s_waitcnt vmcnt(4)" ::: "memory"); }
    __builtin_amdgcn_s_barrier();
    __builtin_amdgcn_s_setprio(1);
    #pragma unroll
    for (int i = 0; i < 4; ++i)
      #pragma unroll
      for (int n = 0; n < 2; ++n)
        #pragma unroll
        for (int kk = 0; kk < 2; ++kk)
          acc[4 + i][2 + n] = __builtin_amdgcn_mfma_f32_16x16x32_bf16(af[i][kk], bf[2 + n][kk], acc[4 + i][2 + n], 0, 0, 0);
    __builtin_amdgcn_s_setprio(0);
    __builtin_amdgcn_s_barrier();
  }

  // epilogue: +bias, C-write (C/D layout: col=lane&15, row=(lane>>4)*4+q)
  #pragma unroll
  for (int ni = 0; ni < 4; ++ni) {
    int col = n0 + (ni & 1) * 16 + wn * 32 + (ni >> 1) * 128 + (lane & 15);
    float bv = bias[col];
    #pragma unroll
    for (int mi = 0; mi < 8; ++mi) {
      int row0 = m0 + (mi & 3) * 16 + wm * 64 + (mi >> 2) * 128 + ((lane >> 4) << 2);
      #pragma unroll
      for (int q = 0; q < 4; ++q) {
        float v = acc[mi][ni][q] + bv;
        if constexpr (CMODE == 0)
          ((float*)Cv)[(size_t)(row0 + q) * N + col] = v;
        else
          ((ushort*)Cv)[(size_t)(row0 + q) * N + col] = f2b(v);
      }
    }
  }
}

// single-GEMM wrapper
template<int CMODE>
__global__ __launch_bounds__(512, 2)
void gemm8p(const ushort* __restrict__ A, const ushort* __restrict__ Bw,
            const float* __restrict__ bias, void* __restrict__ Cv,
            int M, int N, int K)
{
  extern __shared__ ushort lds[];
  gemm_body<CMODE>(A, Bw, bias, Cv, N, K, lds);
}

// merged QKV projection wrapper: z = 0/1/2 selects input, weight, bias, out
__global__ __launch_bounds__(512, 2)
void gemm8p_qkv(const ushort* __restrict__ Abase, const ushort* __restrict__ Wbase,
                const float* __restrict__ b0, const float* __restrict__ b1,
                const float* __restrict__ b2, ushort* __restrict__ Cbase,
                int M, int N, int K)
{
  extern __shared__ ushort lds[];
  const int z = blockIdx.z;
  const size_t slot = (size_t)M * K;
  const size_t wsl  = (size_t)N * K;
  const float* bias = (z == 0) ? b0 : (z == 1) ? b1 : b2;
  gemm_body<1>(Abase + z * slot, Wbase + z * wsl, bias,
               (void*)(Cbase + z * (size_t)M * N), N, K, lds);
}

// ---------------- MFMA attention, NATURAL V (per position) -----------------
__global__ __launch_bounds__(256)
void attn_mfma2(const ushort* __restrict__ Q, const ushort* __restrict__ Kh,
                const ushort* __restrict__ V, ushort* __restrict__ Ot, int P)
{
  const int lane = threadIdx.x & 63;
  const int wid  = threadIdx.x >> 6;
  const int g = lane >> 4, c = lane & 15;
  const int stride = gridDim.x * 4;

  for (int p = blockIdx.x * 4 + wid; p < P; p += stride) {
    const ushort* qb = Q  + (size_t)p * 1024;
    const ushort* kb = Kh + (size_t)p * 1024;
    const ushort* vb = V  + (size_t)p * 1024;

    bf16x8 qf0 = *reinterpret_cast<const bf16x8*>(qb + c * 64 + g * 8);
    bf16x8 qf1 = *reinterpret_cast<const bf16x8*>(qb + c * 64 + 32 + g * 8);
    bf16x8 kf0 = *reinterpret_cast<const bf16x8*>(kb + c * 64 + g * 8);
    bf16x8 kf1 = *reinterpret_cast<const bf16x8*>(kb + c * 64 + 32 + g * 8);

    f32x4 s = {};
    s = __builtin_amdgcn_mfma_f32_16x16x32_bf16(kf0, qf0, s, 0, 0, 0);
    s = __builtin_amdgcn_mfma_f32_16x16x32_bf16(kf1, qf1, s, 0, 0, 0);

    float s0 = s[0] * 0.125f, s1 = s[1] * 0.125f;
    float s2 = s[2] * 0.125f, s3 = s[3] * 0.125f;
    float m = fmaxf(fmaxf(s0, s1), fmaxf(s2, s3));
    m = fmaxf(m, __shfl_xor(m, 16));
    m = fmaxf(m, __shfl_xor(m, 32));
    float e0 = __expf(s0 - m), e1 = __expf(s1 - m);
    float e2 = __expf(s2 - m), e3 = __expf(s3 - m);
    float sum = e0 + e1 + e2 + e3;
    sum += __shfl_xor(sum, 16);
    sum += __shfl_xor(sum, 32);
    float r = 1.0f / sum;

    uint pk0 = (uint)f2b(e0 * r) | ((uint)f2b(e1 * r) << 16);  // P[c][4g+0,1]
    uint pk1 = (uint)f2b(e2 * r) | ((uint)f2b(e3 * r) << 16);  // P[c][4g+2,3]

    int srcA = (((2 * g) & 3) << 4) | c;
    int srcB = (((2 * g + 1) & 3) << 4) | c;
    uint a0 = (uint)__shfl((int)pk0, srcA);
    uint a1 = (uint)__shfl((int)pk1, srcA);
    uint a2 = (uint)__shfl((int)pk0, srcB);
    uint a3 = (uint)__shfl((int)pk1, srcB);
    if (g >= 2) { a0 = 0; a1 = 0; a2 = 0; a3 = 0; }
    union { uint u[4]; bf16x8 v; } pa;
    pa.u[0] = a0; pa.u[1] = a1; pa.u[2] = a2; pa.u[3] = a3;

    ushort* ob = Ot + (size_t)p * 1024;
    #pragma unroll
    for (int blk = 0; blk < 4; ++blk) {
      union { ushort u[8]; bf16x8 v; } vf;
      #pragma unroll
      for (int e = 0; e < 8; ++e)
        vf.u[e] = vb[(8 * (g & 1) + e) * 64 + blk * 16 + c];
      f32x4 o = {};
      o = __builtin_amdgcn_mfma_f32_16x16x32_bf16(pa.v, vf.v, o, 0, 0, 0);
      uint lo = (uint)f2b(o[0]) | ((uint)f2b(o[1]) << 16);
      uint hi = (uint)f2b(o[2]) | ((uint)f2b(o[3]) << 16);
      uint2 w2; w2.x = lo; w2.y = hi;
      *reinterpret_cast<uint2*>(ob + blk * 256 + g * 64 + c * 4) = w2;
    }
  }
}

// --------- fallback GEMM (round-1, fp32 reg-staged, XOR-swizzled LDS) ------
template<bool A_IS_BF16, bool OUT_BF16>
__global__ __launch_bounds__(256)
void gemm_bt(const void* __restrict__ Av, const float* __restrict__ B,
             const float* __restrict__ bias, void* __restrict__ Cv,
             int M, int N, int K)
{
  __shared__ ushort As[BM * BK];
  __shared__ ushort Bs[BN * BK];

  const int tid  = threadIdx.x;
  const int lane = tid & 63;
  const int wid  = tid >> 6;
  const int wr   = wid >> 1;
  const int wc   = wid & 1;
  const int m0   = blockIdx.y * BM;
  const int n0   = blockIdx.x * BN;

  f32x4 acc[4][4] = {};

  const int r   = tid >> 1;
  const int seg = (tid & 1) * 32;

  for (int k0 = 0; k0 < K; k0 += BK) {
    {
      ushort tmp[32];
      if constexpr (A_IS_BF16) {
        const ushort* gA = (const ushort*)Av + (size_t)(m0 + r) * K + k0 + seg;
        #pragma unroll
        for (int u = 0; u < 4; ++u)
          *reinterpret_cast<uint4*>(&tmp[u * 8]) =
              *reinterpret_cast<const uint4*>(gA + u * 8);
      } else {
        const float* gA = (const float*)Av + (size_t)(m0 + r) * K + k0 + seg;
        #pragma unroll
        for (int u = 0; u < 8; ++u) {
          float4 f = *reinterpret_cast<const float4*>(gA + u * 4);
          tmp[u * 4 + 0] = f2b(f.x); tmp[u * 4 + 1] = f2b(f.y);
          tmp[u * 4 + 2] = f2b(f.z); tmp[u * 4 + 3] = f2b(f.w);
        }
      }
      #pragma unroll
      for (int s4 = 0; s4 < 4; ++s4) {
        int slot = (seg >> 3) + s4;
        int byte = r * 128 + ((slot ^ (r & 7)) << 4);
        *reinterpret_cast<uint4*>((char*)As + byte) =
            *reinterpret_cast<uint4*>(&tmp[s4 * 8]);
      }
    }
    {
      const float* gB = B + (size_t)(n0 + r) * K + k0 + seg;
      ushort tmp[32];
      #pragma unroll
      for (int u = 0; u < 8; ++u) {
        float4 f = *reinterpret_cast<const float4*>(gB + u * 4);
        tmp[u * 4 + 0] = f2b(f.x); tmp[u * 4 + 1] = f2b(f.y);
        tmp[u * 4 + 2] = f2b(f.z); tmp[u * 4 + 3] = f2b(f.w);
      }
      #pragma unroll
      for (int s4 = 0; s4 < 4; ++s4) {
        int slot = (seg >> 3) + s4;
        int byte = r * 128 + ((slot ^ (r & 7)) << 4);
        *reinterpret_cast<uint4*>((char*)Bs + byte) =
            *reinterpret_cast<uint4*>(&tmp[s4 * 8]);
      }
    }
    __syncthreads();

    #pragma unroll
    for (int kk = 0; kk < 2; ++kk) {
      const int kbase = kk * 32 + ((lane >> 4) << 3);
      const int slot  = kbase >> 3;
      bf16x8 af[4], bfr[4];
      #pragma unroll
      for (int mi = 0; mi < 4; ++mi) {
        int row = wr * 64 + mi * 16 + (lane & 15);
        af[mi] = *reinterpret_cast<const bf16x8*>(
            (const char*)As + row * 128 + ((slot ^ (row & 7)) << 4));
      }
      #pragma unroll
      for (int ni = 0; ni < 4; ++ni) {
        int row = wc * 64 + ni * 16 + (lane & 15);
        bfr[ni] = *reinterpret_cast<const bf16x8*>(
            (const char*)Bs + row * 128 + ((slot ^ (row & 7)) << 4));
      }
      #pragma unroll
      for (int mi = 0; mi < 4; ++mi)
        #pragma unroll
        for (int ni = 0; ni < 4; ++ni)
          acc[mi][ni] = __builtin_amdgcn_mfma_f32_16x16x32_bf16(
              af[mi], bfr[ni], acc[mi][ni], 0, 0, 0);
    }
    __syncthreads();
  }

  #pragma unroll
  for (int ni = 0; ni < 4; ++ni) {
    int col = n0 + wc * 64 + ni * 16 + (lane & 15);
    float bv = bias[col];
    #pragma unroll
    for (int mi = 0; mi < 4; ++mi) {
      int row0 = m0 + wr * 64 + mi * 16 + ((lane >> 4) << 2);
      #pragma unroll
      for (int q = 0; q < 4; ++q) {
        float v = acc[mi][ni][q] + bv;
        if constexpr (OUT_BF16)
          ((ushort*)Cv)[(size_t)(row0 + q) * N + col] = f2b(v);
        else
          ((float*)Cv)[(size_t)(row0 + q) * N + col] = v;
      }
    }
  }
}

// ------------- fallback attention (round-1, LDS scalar) --------------------
__global__ __launch_bounds__(256)
void attn_kernel(const ushort* __restrict__ Q, const ushort* __restrict__ Kh,
                 const ushort* __restrict__ V, ushort* __restrict__ O)
{
  __shared__ float smem[4][3][16][68];
  const int tid  = threadIdx.x;
  const int wid  = tid >> 6;
  const int lane = tid & 63;
  const size_t p = (size_t)blockIdx.x * 4 + wid;

  {
    const ushort* srcs[3] = { Q + p * 1024, Kh + p * 1024, V + p * 1024 };
    const int i  = lane >> 2;
    const int d0 = (lane & 3) * 16;
    #pragma unroll
    for (int m = 0; m < 3; ++m) {
      const ushort* s = srcs[m] + lane * 16;
      ushort u[16];
      *reinterpret_cast<uint4*>(&u[0]) = *reinterpret_cast<const uint4*>(s);
      *reinterpret_cast<uint4*>(&u[8]) = *reinterpret_cast<const uint4*>(s + 8);
      #pragma unroll
      for (int e = 0; e < 16; ++e) smem[wid][m][i][d0 + e] = bf2f(u[e]);
    }
  }
  __syncthreads();

  const int i  = lane >> 2;
  const int jg = lane & 3;
  const float* qrow = smem[wid][0][i];
  const float* k0r = smem[wid][1][jg * 4 + 0];
  const float* k1r = smem[wid][1][jg * 4 + 1];
  const float* k2r = smem[wid][1][jg * 4 + 2];
  const float* k3r = smem[wid][1][jg * 4 + 3];

  float s0 = 0.f, s1 = 0.f, s2 = 0.f, s3 = 0.f;
  #pragma unroll
  for (int d = 0; d < 64; ++d) {
    float qv = qrow[d];
    s0 += qv * k0r[d]; s1 += qv * k1r[d];
    s2 += qv * k2r[d]; s3 += qv * k3r[d];
  }
  const float scale = 0.125f;
  s0 *= scale; s1 *= scale; s2 *= scale; s3 *= scale;

  float mx = fmaxf(fmaxf(s0, s1), fmaxf(s2, s3));
  mx = fmaxf(mx, __shfl_xor(mx, 1));
  mx = fmaxf(mx, __shfl_xor(mx, 2));
  float e0 = __expf(s0 - mx), e1 = __expf(s1 - mx);
  float e2 = __expf(s2 - mx), e3 = __expf(s3 - mx);
  float sum = e0 + e1 + e2 + e3;
  sum += __shfl_xor(sum, 1);
  sum += __shfl_xor(sum, 2);
  float inv = 1.0f / sum;
  e0 *= inv; e1 *= inv; e2 *= inv; e3 *= inv;

  const float* v0r = smem[wid][2][jg * 4 + 0];
  const float* v1r = smem[wid][2][jg * 4 + 1];
  const float* v2r = smem[wid][2][jg * 4 + 2];
  const float* v3r = smem[wid][2][jg * 4 + 3];
  ushort* orow = O + p * 1024 + i * 64;

  #pragma unroll
  for (int cc = 0; cc < 4; ++cc) {
    float po[16];
    #pragma unroll
    for (int dd = 0; dd < 16; ++dd) {
      int d = cc * 16 + dd;
      po[dd] = e0 * v0r[d] + e1 * v1r[d] + e2 * v2r[d] + e3 * v3r[d];
    }
    #pragma unroll
    for (int dd = 0; dd < 16; ++dd) {
      po[dd] += __shfl_xor(po[dd], 1);
      po[dd] += __shfl_xor(po[dd], 2);
    }
    if (jg == cc) {
      #pragma unroll
      for (int dd = 0; dd < 16; ++dd) orow[cc * 16 + dd] = f2b(po[dd]);
    }
  }
}

extern "C" void kernel_launch(void* const* d_in, const int* in_sizes, int n_in,
                              void* d_out, int out_size, void* d_ws, size_t ws_size,
                              hipStream_t stream)
{
  const float* query = (const float*)d_in[0];
  const float* key_  = (const float*)d_in[1];
  const float* value = (const float*)d_in[2];
  const float* wq_w  = (const float*)d_in[3];
  const float* wq_b  = (const float*)d_in[4];
  const float* wk_w  = (const float*)d_in[5];
  const float* wk_b  = (const float*)d_in[6];
  const float* wv_w  = (const float*)d_in[7];
  const float* wv_b  = (const float*)d_in[8];
  const float* fo_w  = (const float*)d_in[9];
  const float* fo_b  = (const float*)d_in[10];

  const int K = 1024, N = 1024;
  const int M = in_sizes[0] / K;       // 16384
  const size_t slot = (size_t)M * N;
  const size_t wsl  = (size_t)N * K;
  const size_t need_big = (6 * slot + 4 * wsl) * sizeof(ushort);  // 200 MiB
  const size_t need_mid = (4 * slot + 4 * wsl) * sizeof(ushort);  // 136 MiB
  const bool dims_ok = (M % 256) == 0 && N == 1024 && K == 1024;

  const int n8w = (int)(wsl / 8);       // 131072
  const int n8s = (int)(slot / 8);

  if (ws_size >= need_big && dims_ok) {
    hipFuncSetAttribute(reinterpret_cast<const void*>(gemm8p<0>),
                        hipFuncAttributeMaxDynamicSharedMemorySize, 65536);
    hipFuncSetAttribute(reinterpret_cast<const void*>(gemm8p_qkv),
                        hipFuncAttributeMaxDynamicSharedMemorySize, 65536);

    ushort* I0 = (ushort*)d_ws;           // q,k,v bf16 inputs (contiguous)
    ushort* P1 = I0 + 3 * slot;           // Q,K,V projections (contiguous)
    ushort* Wq = P1 + 3 * slot;           // Wq,Wk,Wv contiguous
    ushort* Wo = Wq + 3 * wsl;            // permuted-k Wo
    ushort* Ot = I0;                      // attn out reuses input slot 0

    dim3 g8(N / 256, M / 256);            // (4, 64)
    dim3 g8z(N / 256, M / 256, 3);        // merged QKV
    dim3 b8(512);

    cvt_in3<<<dim3((3 * n8s + 255) / 256), dim3(256), 0, stream>>>(
        query, key_, value, I0, n8s);
    cvt_in3<<<dim3((3 * n8w + 255) / 256), dim3(256), 0, stream>>>(
        wq_w, wk_w, wv_w, Wq, n8w);
    cvt_wo_perm<<<dim3(512), dim3(256), 0, stream>>>(fo_w, Wo);

    gemm8p_qkv<<<g8z, b8, 65536, stream>>>(I0, Wq, wq_b, wk_b, wv_b, P1, M, N, K);

    attn_mfma2<<<dim3(2048), dim3(256), 0, stream>>>(
        P1, P1 + slot, P1 + 2 * slot, Ot, M);
    gemm8p<0><<<g8, b8, 65536, stream>>>(Ot, Wo, fo_b, d_out, M, N, K);
  } else if (ws_size >= need_mid && dims_ok) {
    hipFuncSetAttribute(reinterpret_cast<const void*>(gemm8p<0>),
                        hipFuncAttributeMaxDynamicSharedMemorySize, 65536);
    hipFuncSetAttribute(reinterpret_cast<const void*>(gemm8p<1>),
                        hipFuncAttributeMaxDynamicSharedMemorySize, 65536);

    ushort* S0 = (ushort*)d_ws;
    ushort* S1 = S0 + slot;
    ushort* S2 = S1 + slot;
    ushort* S3 = S2 + slot;
    ushort* Wq = S3 + slot;
    ushort* Wo = Wq + 3 * wsl;

    dim3 g8(N / 256, M / 256);
    dim3 b8(512);

    cvt_in3<<<dim3((3 * n8w + 255) / 256), dim3(256), 0, stream>>>(
        wq_w, wk_w, wv_w, Wq, n8w);
    cvt_wo_perm<<<dim3(512), dim3(256), 0, stream>>>(fo_w, Wo);

    cvt_f32_bf16<<<dim3((n8s + 255) / 256), dim3(256), 0, stream>>>(query, S0, n8s);
    gemm8p<1><<<g8, b8, 65536, stream>>>(S0, Wq,           wq_b, S1, M, N, K);
    cvt_f32_bf16<<<dim3((n8s + 255) / 256), dim3(256), 0, stream>>>(key_, S0, n8s);
    gemm8p<1><<<g8, b8, 65536, stream>>>(S0, Wq + wsl,     wk_b, S2, M, N, K);
    cvt_f32_bf16<<<dim3((n8s + 255) / 256), dim3(256), 0, stream>>>(value, S0, n8s);
    gemm8p<1><<<g8, b8, 65536, stream>>>(S0, Wq + 2 * wsl, wv_b, S3, M, N, K);

    attn_mfma2<<<dim3(2048), dim3(256), 0, stream>>>(S1, S2, S3, S0, M);
    gemm8p<0><<<g8, b8, 65536, stream>>>(S0, Wo, fo_b, d_out, M, N, K);
  } else {
    dim3 grid(N / BN, M / BM);
    ushort* Qb = (ushort*)d_ws;
    ushort* Kb = Qb + slot;
    ushort* Vb = Kb + slot;
    ushort* Ob = Vb + slot;
    gemm_bt<false, true><<<grid, dim3(256), 0, stream>>>(query, wq_w, wq_b, Qb, M, N, K);
    gemm_bt<false, true><<<grid, dim3(256), 0, stream>>>(key_,  wk_w, wk_b, Kb, M, N, K);
    gemm_bt<false, true><<<grid, dim3(256), 0, stream>>>(value, wv_w, wv_b, Vb, M, N, K);
    attn_kernel<<<dim3(M / 4), dim3(256), 0, stream>>>(Qb, Kb, Vb, Ob);
    gemm_bt<true, false><<<grid, dim3(256), 0, stream>>>(Ob, fo_w, fo_b, d_out, M, N, K);
  }
}

// Round 13
// 228.484 us; speedup vs baseline: 6.1059x; 1.0079x over previous
//
#include <hip/hip_runtime.h>
#include <hip/hip_bf16.h>

// CrossAttention (bug-faithful: per-position attention across the 16 heads).
// Round 13: R12 base; per-phase hardware lgkmcnt(0) drain MOVED to after the
// MFMA cluster (WAR fence before closing barrier), pre-MFMA drain and
// sched_barrier(0) removed -> compiler emits fine-grained descending lgkmcnt
// so MFMAs start as soon as their first fragments arrive. All else = R12.

typedef __attribute__((ext_vector_type(8))) __bf16 bf16x8;
typedef __attribute__((ext_vector_type(4))) float f32x4;

#define BM 128
#define BN 128
#define BK 64

__device__ __forceinline__ float bf2f(ushort u) {
  union { unsigned int i; float f; } c; c.i = ((unsigned int)u) << 16; return c.f;
}
__device__ __forceinline__ ushort f2b(float f) {
  union { float f; unsigned int i; } c; c.f = f;
  unsigned int x = c.i;
  return (ushort)((x + 0x7FFFu + ((x >> 16) & 1u)) >> 16);  // RNE
}

// ---------------- fp32 -> bf16 convert (single source) ---------------------
__global__ __launch_bounds__(256)
void cvt_f32_bf16(const float* __restrict__ s, ushort* __restrict__ d, int n8)
{
  int i = blockIdx.x * 256 + threadIdx.x;
  if (i >= n8) return;
  const float4* sp = reinterpret_cast<const float4*>(s) + (size_t)i * 2;
  float4 a = sp[0], b = sp[1];
  ushort u[8] = { f2b(a.x), f2b(a.y), f2b(a.z), f2b(a.w),
                  f2b(b.x), f2b(b.y), f2b(b.z), f2b(b.w) };
  reinterpret_cast<uint4*>(d)[i] = *reinterpret_cast<uint4*>(u);
}

// ------------- three converts in one launch (dst contiguous) ---------------
__global__ __launch_bounds__(256)
void cvt_in3(const float* __restrict__ a, const float* __restrict__ b,
             const float* __restrict__ c, ushort* __restrict__ dst, int n8each)
{
  int i = blockIdx.x * 256 + threadIdx.x;
  if (i >= 3 * n8each) return;
  const float* s; int j;
  if (i < n8each)          { s = a; j = i; }
  else if (i < 2 * n8each) { s = b; j = i - n8each; }
  else                     { s = c; j = i - 2 * n8each; }
  const float4* sp = reinterpret_cast<const float4*>(s) + (size_t)j * 2;
  float4 x = sp[0], y = sp[1];
  ushort u[8] = { f2b(x.x), f2b(x.y), f2b(x.z), f2b(x.w),
                  f2b(y.x), f2b(y.y), f2b(y.z), f2b(y.w) };
  reinterpret_cast<uint4*>(dst)[i] = *reinterpret_cast<uint4*>(u);
}

// --------- Wo convert with inverse k-permutation (matches Ot layout) -------
// Ot element idx holds O[i=4g+q][d=blk*16+c], idx = blk*256 + g*64 + c*4 + q.
__global__ __launch_bounds__(256)
void cvt_wo_perm(const float* __restrict__ w, ushort* __restrict__ o)
{
  int t = blockIdx.x * 256 + threadIdx.x;   // 0 .. 131071
  int n  = t >> 7;
  int i8 = (t & 127) << 3;
  int blk = i8 >> 8, g = (i8 >> 6) & 3, c = (i8 >> 2) & 15;
  const float* src = w + (size_t)n * 1024 + 4 * g * 64 + blk * 16 + c;
  ushort u[8];
  #pragma unroll
  for (int j = 0; j < 8; ++j)
    u[j] = f2b(src[(j & 3) * 64 + (j >> 2)]);
  *reinterpret_cast<uint4*>(o + (size_t)n * 1024 + i8) = *reinterpret_cast<uint4*>(u);
}

// ---------- 4-phase 256x256x64 bf16 GEMM body, 64KB single-buffered --------
// LDS: A [256][64] bf16 at 0 (32KB), B at 16384 ushorts (32KB). Halves of
// tile t+1 staged the phase after their region's reads retire:
// AloBlo@P1, Bhi@P2, Ahi@P3. Guards (FIFO): P0 vmcnt(2) retires Bhi(t);
// P1 vmcnt(4) retires Ahi(t); P3 vmcnt(4) retires AloBlo(t+1).
// Per phase: reads -> stage+vmcnt -> barrier -> MFMAs (compiler-scheduled
// lgkmcnt) -> lgkmcnt(0) WAR fence -> barrier.
template<int CMODE>
__device__ __forceinline__
void gemm_body(const ushort* __restrict__ A, const ushort* __restrict__ Bw,
               const float* __restrict__ bias, void* __restrict__ Cv,
               int N, int K, ushort* lds)
{
  const int tid  = threadIdx.x;
  const int lane = tid & 63;
  const int wid  = tid >> 6;         // 0..7
  const int wm   = wid >> 2;         // 0..1
  const int wn   = wid & 3;          // 0..3

  const int nwg = gridDim.x * gridDim.y;
  int fid = blockIdx.y * gridDim.x + blockIdx.x;
  if ((nwg & 7) == 0) fid = (fid & 7) * (nwg >> 3) + (fid >> 3);
  const int bx = fid % gridDim.x;
  const int by = fid / gridDim.x;
  const int m0 = by * 256, n0 = bx * 256;

  const int NT = K >> 6;

  const int csw = ((lane & 7) ^ (lane >> 3)) << 3;   // pre-swizzled col offset
  // h: 0=A-lo, 1=A-hi, 2=B-lo, 3=B-hi (each 2 gload_lds)
  auto STAGE = [&](int h, int kt) {
    const ushort* base = (h >= 2) ? Bw : A;
    const int o0 = (h >= 2) ? n0 : m0;
    const int rl = (h & 1) * 128;
    #pragma unroll
    for (int j = 0; j < 2; ++j) {
      int rt = rl + j * 64 + wid * 8;
      const ushort* src = base + (size_t)(o0 + rt + (lane >> 3)) * K + kt * 64 + csw;
      ushort* dst = lds + (h >= 2 ? 16384 : 0) + rt * 64;
      __builtin_amdgcn_global_load_lds(
          (const __attribute__((address_space(1))) void*)src,
          (__attribute__((address_space(3))) void*)dst, 16, 0, 0);
    }
  };

  auto LDA = [&](int mi, int kk) -> bf16x8 {
    int row  = (mi & 3) * 16 + wm * 64 + (mi >> 2) * 128 + (lane & 15);
    int slot = kk * 4 + (lane >> 4);
    int byte = row * 128 + (((slot ^ (row & 7)) & 7) << 4);
    return *reinterpret_cast<const bf16x8*>((const char*)lds + byte);
  };
  auto LDB = [&](int ni, int kk) -> bf16x8 {
    int row  = (ni & 1) * 16 + wn * 32 + (ni >> 1) * 128 + (lane & 15);
    int slot = kk * 4 + (lane >> 4);
    int byte = row * 128 + (((slot ^ (row & 7)) & 7) << 4);
    return *reinterpret_cast<const bf16x8*>((const char*)(lds + 16384) + byte);
  };

  f32x4 acc[8][4] = {};
  bf16x8 af[4][2], bf[4][2];

  // prologue: stage tile 0 (FIFO: Alo, Blo, Bhi, Ahi); retire Alo+Blo.
  STAGE(0, 0); STAGE(2, 0); STAGE(3, 0); STAGE(1, 0);
  asm volatile("s_waitcnt vmcnt(4)" ::: "memory");
  __builtin_amdgcn_s_barrier();

  for (int t = 0; t < NT; ++t) {
    const bool pf = (t + 1) < NT;

    // ---- P0: reads Alo,Blo; guard retires Bhi(t) for P1 ----
    #pragma unroll
    for (int i = 0; i < 4; ++i) { af[i][0] = LDA(i, 0); af[i][1] = LDA(i, 1); }
    #pragma unroll
    for (int n = 0; n < 2; ++n) { bf[n][0] = LDB(n, 0); bf[n][1] = LDB(n, 1); }
    asm volatile("s_waitcnt vmcnt(2)" ::: "memory");
    __builtin_amdgcn_s_barrier();
    __builtin_amdgcn_s_setprio(1);
    #pragma unroll
    for (int i = 0; i < 4; ++i)
      #pragma unroll
      for (int n = 0; n < 2; ++n)
        #pragma unroll
        for (int kk = 0; kk < 2; ++kk)
          acc[i][n] = __builtin_amdgcn_mfma_f32_16x16x32_bf16(af[i][kk], bf[n][kk], acc[i][n], 0, 0, 0);
    __builtin_amdgcn_s_setprio(0);
    asm volatile("s_waitcnt lgkmcnt(0)" ::: "memory");   // WAR fence: reads retired
    __builtin_amdgcn_s_barrier();

    // ---- P1: stage Alo,Blo(t+1); reads Bhi; guard retires Ahi(t) ----
    if (pf) { STAGE(0, t + 1); STAGE(2, t + 1); }
    #pragma unroll
    for (int n = 0; n < 2; ++n) { bf[2 + n][0] = LDB(2 + n, 0); bf[2 + n][1] = LDB(2 + n, 1); }
    if (pf) asm volatile("s_waitcnt vmcnt(4)" ::: "memory");
    else    asm volatile("s_waitcnt vmcnt(0)" ::: "memory");
    __builtin_amdgcn_s_barrier();
    __builtin_amdgcn_s_setprio(1);
    #pragma unroll
    for (int i = 0; i < 4; ++i)
      #pragma unroll
      for (int n = 0; n < 2; ++n)
        #pragma unroll
        for (int kk = 0; kk < 2; ++kk)
          acc[i][2 + n] = __builtin_amdgcn_mfma_f32_16x16x32_bf16(af[i][kk], bf[2 + n][kk], acc[i][2 + n], 0, 0, 0);
    __builtin_amdgcn_s_setprio(0);
    asm volatile("s_waitcnt lgkmcnt(0)" ::: "memory");
    __builtin_amdgcn_s_barrier();

    // ---- P2: stage Bhi(t+1); reads Ahi ----
    if (pf) STAGE(3, t + 1);
    #pragma unroll
    for (int i = 0; i < 4; ++i) { af[i][0] = LDA(4 + i, 0); af[i][1] = LDA(4 + i, 1); }
    __builtin_amdgcn_s_barrier();
    __builtin_amdgcn_s_setprio(1);
    #pragma unroll
    for (int i = 0; i < 4; ++i)
      #pragma unroll
      for (int n = 0; n < 2; ++n)
        #pragma unroll
        for (int kk = 0; kk < 2; ++kk)
          acc[4 + i][n] = __builtin_amdgcn_mfma_f32_16x16x32_bf16(af[i][kk], bf[n][kk], acc[4 + i][n], 0, 0, 0);
    __builtin_amdgcn_s_setprio(0);
    asm volatile("s_waitcnt lgkmcnt(0)" ::: "memory");
    __builtin_amdgcn_s_barrier();

    // ---- P3: stage Ahi(t+1); guard retires AloBlo(t+1) for next P0 ----
    if (pf) { STAGE(1, t + 1);
              asm volatile("s_waitcnt vmcnt(4)" ::: "memory"); }
    __builtin_amdgcn_s_barrier();
    __builtin_amdgcn_s_setprio(1);
    #pragma unroll
    for (int i = 0; i < 4; ++i)
      #pragma unroll
      for (int n = 0; n < 2; ++n)
        #pragma unroll
        for (int kk = 0; kk < 2; ++kk)
          acc[4 + i][2 + n] = __builtin_amdgcn_mfma_f32_16x16x32_bf16(af[i][kk], bf[2 + n][kk], acc[4 + i][2 + n], 0, 0, 0);
    __builtin_amdgcn_s_setprio(0);
    __builtin_amdgcn_s_barrier();
  }

  // epilogue: +bias, C-write (C/D layout: col=lane&15, row=(lane>>4)*4+q)
  #pragma unroll
  for (int ni = 0; ni < 4; ++ni) {
    int col = n0 + (ni & 1) * 16 + wn * 32 + (ni >> 1) * 128 + (lane & 15);
    float bv = bias[col];
    #pragma unroll
    for (int mi = 0; mi < 8; ++mi) {
      int row0 = m0 + (mi & 3) * 16 + wm * 64 + (mi >> 2) * 128 + ((lane >> 4) << 2);
      #pragma unroll
      for (int q = 0; q < 4; ++q) {
        float v = acc[mi][ni][q] + bv;
        if constexpr (CMODE == 0)
          ((float*)Cv)[(size_t)(row0 + q) * N + col] = v;
        else
          ((ushort*)Cv)[(size_t)(row0 + q) * N + col] = f2b(v);
      }
    }
  }
}

// single-GEMM wrapper
template<int CMODE>
__global__ __launch_bounds__(512, 2)
void gemm8p(const ushort* __restrict__ A, const ushort* __restrict__ Bw,
            const float* __restrict__ bias, void* __restrict__ Cv,
            int M, int N, int K)
{
  extern __shared__ ushort lds[];
  gemm_body<CMODE>(A, Bw, bias, Cv, N, K, lds);
}

// merged QKV projection wrapper: z = 0/1/2 selects input, weight, bias, out
__global__ __launch_bounds__(512, 2)
void gemm8p_qkv(const ushort* __restrict__ Abase, const ushort* __restrict__ Wbase,
                const float* __restrict__ b0, const float* __restrict__ b1,
                const float* __restrict__ b2, ushort* __restrict__ Cbase,
                int M, int N, int K)
{
  extern __shared__ ushort lds[];
  const int z = blockIdx.z;
  const size_t slot = (size_t)M * K;
  const size_t wsl  = (size_t)N * K;
  const float* bias = (z == 0) ? b0 : (z == 1) ? b1 : b2;
  gemm_body<1>(Abase + z * slot, Wbase + z * wsl, bias,
               (void*)(Cbase + z * (size_t)M * N), N, K, lds);
}

// ---------------- MFMA attention, NATURAL V (per position) -----------------
__global__ __launch_bounds__(256)
void attn_mfma2(const ushort* __restrict__ Q, const ushort* __restrict__ Kh,
                const ushort* __restrict__ V, ushort* __restrict__ Ot, int P)
{
  const int lane = threadIdx.x & 63;
  const int wid  = threadIdx.x >> 6;
  const int g = lane >> 4, c = lane & 15;
  const int stride = gridDim.x * 4;

  for (int p = blockIdx.x * 4 + wid; p < P; p += stride) {
    const ushort* qb = Q  + (size_t)p * 1024;
    const ushort* kb = Kh + (size_t)p * 1024;
    const ushort* vb = V  + (size_t)p * 1024;

    bf16x8 qf0 = *reinterpret_cast<const bf16x8*>(qb + c * 64 + g * 8);
    bf16x8 qf1 = *reinterpret_cast<const bf16x8*>(qb + c * 64 + 32 + g * 8);
    bf16x8 kf0 = *reinterpret_cast<const bf16x8*>(kb + c * 64 + g * 8);
    bf16x8 kf1 = *reinterpret_cast<const bf16x8*>(kb + c * 64 + 32 + g * 8);

    f32x4 s = {};
    s = __builtin_amdgcn_mfma_f32_16x16x32_bf16(kf0, qf0, s, 0, 0, 0);
    s = __builtin_amdgcn_mfma_f32_16x16x32_bf16(kf1, qf1, s, 0, 0, 0);

    float s0 = s[0] * 0.125f, s1 = s[1] * 0.125f;
    float s2 = s[2] * 0.125f, s3 = s[3] * 0.125f;
    float m = fmaxf(fmaxf(s0, s1), fmaxf(s2, s3));
    m = fmaxf(m, __shfl_xor(m, 16));
    m = fmaxf(m, __shfl_xor(m, 32));
    float e0 = __expf(s0 - m), e1 = __expf(s1 - m);
    float e2 = __expf(s2 - m), e3 = __expf(s3 - m);
    float sum = e0 + e1 + e2 + e3;
    sum += __shfl_xor(sum, 16);
    sum += __shfl_xor(sum, 32);
    float r = 1.0f / sum;

    uint pk0 = (uint)f2b(e0 * r) | ((uint)f2b(e1 * r) << 16);  // P[c][4g+0,1]
    uint pk1 = (uint)f2b(e2 * r) | ((uint)f2b(e3 * r) << 16);  // P[c][4g+2,3]

    int srcA = (((2 * g) & 3) << 4) | c;
    int srcB = (((2 * g + 1) & 3) << 4) | c;
    uint a0 = (uint)__shfl((int)pk0, srcA);
    uint a1 = (uint)__shfl((int)pk1, srcA);
    uint a2 = (uint)__shfl((int)pk0, srcB);
    uint a3 = (uint)__shfl((int)pk1, srcB);
    if (g >= 2) { a0 = 0; a1 = 0; a2 = 0; a3 = 0; }
    union { uint u[4]; bf16x8 v; } pa;
    pa.u[0] = a0; pa.u[1] = a1; pa.u[2] = a2; pa.u[3] = a3;

    ushort* ob = Ot + (size_t)p * 1024;
    #pragma unroll
    for (int blk = 0; blk < 4; ++blk) {
      union { ushort u[8]; bf16x8 v; } vf;
      #pragma unroll
      for (int e = 0; e < 8; ++e)
        vf.u[e] = vb[(8 * (g & 1) + e) * 64 + blk * 16 + c];
      f32x4 o = {};
      o = __builtin_amdgcn_mfma_f32_16x16x32_bf16(pa.v, vf.v, o, 0, 0, 0);
      uint lo = (uint)f2b(o[0]) | ((uint)f2b(o[1]) << 16);
      uint hi = (uint)f2b(o[2]) | ((uint)f2b(o[3]) << 16);
      uint2 w2; w2.x = lo; w2.y = hi;
      *reinterpret_cast<uint2*>(ob + blk * 256 + g * 64 + c * 4) = w2;
    }
  }
}

// --------- fallback GEMM (round-1, fp32 reg-staged, XOR-swizzled LDS) ------
template<bool A_IS_BF16, bool OUT_BF16>
__global__ __launch_bounds__(256)
void gemm_bt(const void* __restrict__ Av, const float* __restrict__ B,
             const float* __restrict__ bias, void* __restrict__ Cv,
             int M, int N, int K)
{
  __shared__ ushort As[BM * BK];
  __shared__ ushort Bs[BN * BK];

  const int tid  = threadIdx.x;
  const int lane = tid & 63;
  const int wid  = tid >> 6;
  const int wr   = wid >> 1;
  const int wc   = wid & 1;
  const int m0   = blockIdx.y * BM;
  const int n0   = blockIdx.x * BN;

  f32x4 acc[4][4] = {};

  const int r   = tid >> 1;
  const int seg = (tid & 1) * 32;

  for (int k0 = 0; k0 < K; k0 += BK) {
    {
      ushort tmp[32];
      if constexpr (A_IS_BF16) {
        const ushort* gA = (const ushort*)Av + (size_t)(m0 + r) * K + k0 + seg;
        #pragma unroll
        for (int u = 0; u < 4; ++u)
          *reinterpret_cast<uint4*>(&tmp[u * 8]) =
              *reinterpret_cast<const uint4*>(gA + u * 8);
      } else {
        const float* gA = (const float*)Av + (size_t)(m0 + r) * K + k0 + seg;
        #pragma unroll
        for (int u = 0; u < 8; ++u) {
          float4 f = *reinterpret_cast<const float4*>(gA + u * 4);
          tmp[u * 4 + 0] = f2b(f.x); tmp[u * 4 + 1] = f2b(f.y);
          tmp[u * 4 + 2] = f2b(f.z); tmp[u * 4 + 3] = f2b(f.w);
        }
      }
      #pragma unroll
      for (int s4 = 0; s4 < 4; ++s4) {
        int slot = (seg >> 3) + s4;
        int byte = r * 128 + ((slot ^ (r & 7)) << 4);
        *reinterpret_cast<uint4*>((char*)As + byte) =
            *reinterpret_cast<uint4*>(&tmp[s4 * 8]);
      }
    }
    {
      const float* gB = B + (size_t)(n0 + r) * K + k0 + seg;
      ushort tmp[32];
      #pragma unroll
      for (int u = 0; u < 8; ++u) {
        float4 f = *reinterpret_cast<const float4*>(gB + u * 4);
        tmp[u * 4 + 0] = f2b(f.x); tmp[u * 4 + 1] = f2b(f.y);
        tmp[u * 4 + 2] = f2b(f.z); tmp[u * 4 + 3] = f2b(f.w);
      }
      #pragma unroll
      for (int s4 = 0; s4 < 4; ++s4) {
        int slot = (seg >> 3) + s4;
        int byte = r * 128 + ((slot ^ (r & 7)) << 4);
        *reinterpret_cast<uint4*>((char*)Bs + byte) =
            *reinterpret_cast<uint4*>(&tmp[s4 * 8]);
      }
    }
    __syncthreads();

    #pragma unroll
    for (int kk = 0; kk < 2; ++kk) {
      const int kbase = kk * 32 + ((lane >> 4) << 3);
      const int slot  = kbase >> 3;
      bf16x8 af[4], bfr[4];
      #pragma unroll
      for (int mi = 0; mi < 4; ++mi) {
        int row = wr * 64 + mi * 16 + (lane & 15);
        af[mi] = *reinterpret_cast<const bf16x8*>(
            (const char*)As + row * 128 + ((slot ^ (row & 7)) << 4));
      }
      #pragma unroll
      for (int ni = 0; ni < 4; ++ni) {
        int row = wc * 64 + ni * 16 + (lane & 15);
        bfr[ni] = *reinterpret_cast<const bf16x8*>(
            (const char*)Bs + row * 128 + ((slot ^ (row & 7)) << 4));
      }
      #pragma unroll
      for (int mi = 0; mi < 4; ++mi)
        #pragma unroll
        for (int ni = 0; ni < 4; ++ni)
          acc[mi][ni] = __builtin_amdgcn_mfma_f32_16x16x32_bf16(
              af[mi], bfr[ni], acc[mi][ni], 0, 0, 0);
    }
    __syncthreads();
  }

  #pragma unroll
  for (int ni = 0; ni < 4; ++ni) {
    int col = n0 + wc * 64 + ni * 16 + (lane & 15);
    float bv = bias[col];
    #pragma unroll
    for (int mi = 0; mi < 4; ++mi) {
      int row0 = m0 + wr * 64 + mi * 16 + ((lane >> 4) << 2);
      #pragma unroll
      for (int q = 0; q < 4; ++q) {
        float v = acc[mi][ni][q] + bv;
        if constexpr (OUT_BF16)
          ((ushort*)Cv)[(size_t)(row0 + q) * N + col] = f2b(v);
        else
          ((float*)Cv)[(size_t)(row0 + q) * N + col] = v;
      }
    }
  }
}

// ------------- fallback attention (round-1, LDS scalar) --------------------
__global__ __launch_bounds__(256)
void attn_kernel(const ushort* __restrict__ Q, const ushort* __restrict__ Kh,
                 const ushort* __restrict__ V, ushort* __restrict__ O)
{
  __shared__ float smem[4][3][16][68];
  const int tid  = threadIdx.x;
  const int wid  = tid >> 6;
  const int lane = tid & 63;
  const size_t p = (size_t)blockIdx.x * 4 + wid;

  {
    const ushort* srcs[3] = { Q + p * 1024, Kh + p * 1024, V + p * 1024 };
    const int i  = lane >> 2;
    const int d0 = (lane & 3) * 16;
    #pragma unroll
    for (int m = 0; m < 3; ++m) {
      const ushort* s = srcs[m] + lane * 16;
      ushort u[16];
      *reinterpret_cast<uint4*>(&u[0]) = *reinterpret_cast<const uint4*>(s);
      *reinterpret_cast<uint4*>(&u[8]) = *reinterpret_cast<const uint4*>(s + 8);
      #pragma unroll
      for (int e = 0; e < 16; ++e) smem[wid][m][i][d0 + e] = bf2f(u[e]);
    }
  }
  __syncthreads();

  const int i  = lane >> 2;
  const int jg = lane & 3;
  const float* qrow = smem[wid][0][i];
  const float* k0r = smem[wid][1][jg * 4 + 0];
  const float* k1r = smem[wid][1][jg * 4 + 1];
  const float* k2r = smem[wid][1][jg * 4 + 2];
  const float* k3r = smem[wid][1][jg * 4 + 3];

  float s0 = 0.f, s1 = 0.f, s2 = 0.f, s3 = 0.f;
  #pragma unroll
  for (int d = 0; d < 64; ++d) {
    float qv = qrow[d];
    s0 += qv * k0r[d]; s1 += qv * k1r[d];
    s2 += qv * k2r[d]; s3 += qv * k3r[d];
  }
  const float scale = 0.125f;
  s0 *= scale; s1 *= scale; s2 *= scale; s3 *= scale;

  float mx = fmaxf(fmaxf(s0, s1), fmaxf(s2, s3));
  mx = fmaxf(mx, __shfl_xor(mx, 1));
  mx = fmaxf(mx, __shfl_xor(mx, 2));
  float e0 = __expf(s0 - mx), e1 = __expf(s1 - mx);
  float e2 = __expf(s2 - mx), e3 = __expf(s3 - mx);
  float sum = e0 + e1 + e2 + e3;
  sum += __shfl_xor(sum, 1);
  sum += __shfl_xor(sum, 2);
  float inv = 1.0f / sum;
  e0 *= inv; e1 *= inv; e2 *= inv; e3 *= inv;

  const float* v0r = smem[wid][2][jg * 4 + 0];
  const float* v1r = smem[wid][2][jg * 4 + 1];
  const float* v2r = smem[wid][2][jg * 4 + 2];
  const float* v3r = smem[wid][2][jg * 4 + 3];
  ushort* orow = O + p * 1024 + i * 64;

  #pragma unroll
  for (int cc = 0; cc < 4; ++cc) {
    float po[16];
    #pragma unroll
    for (int dd = 0; dd < 16; ++dd) {
      int d = cc * 16 + dd;
      po[dd] = e0 * v0r[d] + e1 * v1r[d] + e2 * v2r[d] + e3 * v3r[d];
    }
    #pragma unroll
    for (int dd = 0; dd < 16; ++dd) {
      po[dd] += __shfl_xor(po[dd], 1);
      po[dd] += __shfl_xor(po[dd], 2);
    }
    if (jg == cc) {
      #pragma unroll
      for (int dd = 0; dd < 16; ++dd) orow[cc * 16 + dd] = f2b(po[dd]);
    }
  }
}

extern "C" void kernel_launch(void* const* d_in, const int* in_sizes, int n_in,
                              void* d_out, int out_size, void* d_ws, size_t ws_size,
                              hipStream_t stream)
{
  const float* query = (const float*)d_in[0];
  const float* key_  = (const float*)d_in[1];
  const float* value = (const float*)d_in[2];
  const float* wq_w  = (const float*)d_in[3];
  const float* wq_b  = (const float*)d_in[4];
  const float* wk_w  = (const float*)d_in[5];
  const float* wk_b  = (const float*)d_in[6];
  const float* wv_w  = (const float*)d_in[7];
  const float* wv_b  = (const float*)d_in[8];
  const float* fo_w  = (const float*)d_in[9];
  const float* fo_b  = (const float*)d_in[10];

  const int K = 1024, N = 1024;
  const int M = in_sizes[0] / K;       // 16384
  const size_t slot = (size_t)M * N;
  const size_t wsl  = (size_t)N * K;
  const size_t need_big = (6 * slot + 4 * wsl) * sizeof(ushort);  // 200 MiB
  const size_t need_mid = (4 * slot + 4 * wsl) * sizeof(ushort);  // 136 MiB
  const bool dims_ok = (M % 256) == 0 && N == 1024 && K == 1024;

  const int n8w = (int)(wsl / 8);       // 131072
  const int n8s = (int)(slot / 8);

  if (ws_size >= need_big && dims_ok) {
    hipFuncSetAttribute(reinterpret_cast<const void*>(gemm8p<0>),
                        hipFuncAttributeMaxDynamicSharedMemorySize, 65536);
    hipFuncSetAttribute(reinterpret_cast<const void*>(gemm8p_qkv),
                        hipFuncAttributeMaxDynamicSharedMemorySize, 65536);

    ushort* I0 = (ushort*)d_ws;           // q,k,v bf16 inputs (contiguous)
    ushort* P1 = I0 + 3 * slot;           // Q,K,V projections (contiguous)
    ushort* Wq = P1 + 3 * slot;           // Wq,Wk,Wv contiguous
    ushort* Wo = Wq + 3 * wsl;            // permuted-k Wo
    ushort* Ot = I0;                      // attn out reuses input slot 0

    dim3 g8(N / 256, M / 256);            // (4, 64)
    dim3 g8z(N / 256, M / 256, 3);        // merged QKV
    dim3 b8(512);

    cvt_in3<<<dim3((3 * n8s + 255) / 256), dim3(256), 0, stream>>>(
        query, key_, value, I0, n8s);
    cvt_in3<<<dim3((3 * n8w + 255) / 256), dim3(256), 0, stream>>>(
        wq_w, wk_w, wv_w, Wq, n8w);
    cvt_wo_perm<<<dim3(512), dim3(256), 0, stream>>>(fo_w, Wo);

    gemm8p_qkv<<<g8z, b8, 65536, stream>>>(I0, Wq, wq_b, wk_b, wv_b, P1, M, N, K);

    attn_mfma2<<<dim3(2048), dim3(256), 0, stream>>>(
        P1, P1 + slot, P1 + 2 * slot, Ot, M);
    gemm8p<0><<<g8, b8, 65536, stream>>>(Ot, Wo, fo_b, d_out, M, N, K);
  } else if (ws_size >= need_mid && dims_ok) {
    hipFuncSetAttribute(reinterpret_cast<const void*>(gemm8p<0>),
                        hipFuncAttributeMaxDynamicSharedMemorySize, 65536);
    hipFuncSetAttribute(reinterpret_cast<const void*>(gemm8p<1>),
                        hipFuncAttributeMaxDynamicSharedMemorySize, 65536);

    ushort* S0 = (ushort*)d_ws;
    ushort* S1 = S0 + slot;
    ushort* S2 = S1 + slot;
    ushort* S3 = S2 + slot;
    ushort* Wq = S3 + slot;
    ushort* Wo = Wq + 3 * wsl;

    dim3 g8(N / 256, M / 256);
    dim3 b8(512);

    cvt_in3<<<dim3((3 * n8w + 255) / 256), dim3(256), 0, stream>>>(
        wq_w, wk_w, wv_w, Wq, n8w);
    cvt_wo_perm<<<dim3(512), dim3(256), 0, stream>>>(fo_w, Wo);

    cvt_f32_bf16<<<dim3((n8s + 255) / 256), dim3(256), 0, stream>>>(query, S0, n8s);
    gemm8p<1><<<g8, b8, 65536, stream>>>(S0, Wq,           wq_b, S1, M, N, K);
    cvt_f32_bf16<<<dim3((n8s + 255) / 256), dim3(256), 0, stream>>>(key_, S0, n8s);
    gemm8p<1><<<g8, b8, 65536, stream>>>(S0, Wq + wsl,     wk_b, S2, M, N, K);
    cvt_f32_bf16<<<dim3((n8s + 255) / 256), dim3(256), 0, stream>>>(value, S0, n8s);
    gemm8p<1><<<g8, b8, 65536, stream>>>(S0, Wq + 2 * wsl, wv_b, S3, M, N, K);

    attn_mfma2<<<dim3(2048), dim3(256), 0, stream>>>(S1, S2, S3, S0, M);
    gemm8p<0><<<g8, b8, 65536, stream>>>(S0, Wo, fo_b, d_out, M, N, K);
  } else {
    dim3 grid(N / BN, M / BM);
    ushort* Qb = (ushort*)d_ws;
    ushort* Kb = Qb + slot;
    ushort* Vb = Kb + slot;
    ushort* Ob = Vb + slot;
    gemm_bt<false, true><<<grid, dim3(256), 0, stream>>>(query, wq_w, wq_b, Qb, M, N, K);
    gemm_bt<false, true><<<grid, dim3(256), 0, stream>>>(key_,  wk_w, wk_b, Kb, M, N, K);
    gemm_bt<false, true><<<grid, dim3(256), 0, stream>>>(value, wv_w, wv_b, Vb, M, N, K);
    attn_kernel<<<dim3(M / 4), dim3(256), 0, stream>>>(Qb, Kb, Vb, Ob);
    gemm_bt<true, false><<<grid, dim3(256), 0, stream>>>(Ob, fo_w, fo_b, d_out, M, N, K);
  }
}